// Round 1
// baseline (10010.914 us; speedup 1.0000x reference)
//
#include <hip/hip_runtime.h>

#define N_NODES 100000
#define N_EDGES 1600000
#define NODE_NF 11
#define EDGE_NF 4
#define H_NF 128
#define EMB_NF 4

// ---------------------------------------------------------------------------
// Prep: transpose eW2 [k][j] -> W2T [j][k] so edge-kernel phase B reads
// contiguous scalar weight rows (s_load_dwordx16 streams).
// ---------------------------------------------------------------------------
__global__ __launch_bounds__(256)
void transpose_w2(const float* __restrict__ W, float* __restrict__ WT) {
    int i = blockIdx.x * 256 + threadIdx.x;
    if (i < H_NF * H_NF) {
        int k = i >> 7;          // source row
        int j = i & (H_NF - 1);  // source col
        WT[j * H_NF + k] = W[i];
    }
}

// ---------------------------------------------------------------------------
// Edge kernel: thread-per-edge.
// Phase A (layer1 26->128): k rolled, j fully unrolled -> h[128] in VGPRs,
//   inputs gathered once per k (amortized over 128 fmacs), weights uniform
//   -> scalar loads.
// Phase B (layer2 128->128): j0-tile of 8 rolled, k fully unrolled (h[k]
//   static), transposed weights -> contiguous scalar loads. ReLU + atomic
//   scatter into agg[j][row] (feature-major for coalesced node-side reads).
// ---------------------------------------------------------------------------
__global__ __launch_bounds__(256)
void edge_kernel(const float* __restrict__ node_feats,
                 const int*   __restrict__ edge_index,
                 const float* __restrict__ edge_attr,
                 const float* __restrict__ eW1,
                 const float* __restrict__ eb1,
                 const float* __restrict__ W2T,
                 const float* __restrict__ eb2,
                 float* agg)  // [H_NF][N_NODES]
{
    int e = blockIdx.x * 256 + threadIdx.x;
    if (e >= N_EDGES) return;
    int row = edge_index[e];
    int col = edge_index[N_EDGES + e];

    float h[H_NF];
    #pragma unroll
    for (int j = 0; j < H_NF; ++j) h[j] = eb1[j];

    const float* srcp = node_feats + row * NODE_NF;
    #pragma unroll 1
    for (int k = 0; k < NODE_NF; ++k) {
        float x = srcp[k];
        const float* w = eW1 + k * H_NF;
        #pragma unroll
        for (int j = 0; j < H_NF; ++j) h[j] = fmaf(x, w[j], h[j]);
    }
    const float* dstp = node_feats + col * NODE_NF;
    #pragma unroll 1
    for (int k = 0; k < NODE_NF; ++k) {
        float x = dstp[k];
        const float* w = eW1 + (NODE_NF + k) * H_NF;
        #pragma unroll
        for (int j = 0; j < H_NF; ++j) h[j] = fmaf(x, w[j], h[j]);
    }
    float4 at = ((const float4*)edge_attr)[e];
    float av[EDGE_NF] = {at.x, at.y, at.z, at.w};
    #pragma unroll
    for (int k = 0; k < EDGE_NF; ++k) {
        float x = av[k];
        const float* w = eW1 + (2 * NODE_NF + k) * H_NF;
        #pragma unroll
        for (int j = 0; j < H_NF; ++j) h[j] = fmaf(x, w[j], h[j]);
    }
    #pragma unroll
    for (int j = 0; j < H_NF; ++j) h[j] = fmaxf(h[j], 0.f);

    #pragma unroll 1
    for (int j0 = 0; j0 < H_NF; j0 += 8) {
        float acc[8];
        #pragma unroll
        for (int jj = 0; jj < 8; ++jj) acc[jj] = eb2[j0 + jj];
        #pragma unroll
        for (int k = 0; k < H_NF; ++k) {
            float x = h[k];
            #pragma unroll
            for (int jj = 0; jj < 8; ++jj)
                acc[jj] = fmaf(x, W2T[(j0 + jj) * H_NF + k], acc[jj]);
        }
        #pragma unroll
        for (int jj = 0; jj < 8; ++jj) {
            float v = fmaxf(acc[jj], 0.f);
            atomicAdd(&agg[(j0 + jj) * N_NODES + row], v);
        }
    }
}

// ---------------------------------------------------------------------------
// Node kernel 1: thread-per-node. n_h = relu([nf, agg] @ nW1 + nb1).
// agg read coalesced (feature-major). Result written back over the SAME
// buffer (column n is private to thread n: all reads of column n happen
// in this thread before its writes) -> halves workspace need.
// ---------------------------------------------------------------------------
__global__ __launch_bounds__(256)
void node_kernel1(const float* __restrict__ node_feats,
                  float* agg_nh,  // in: agg [H][N]; out: n_h [H][N] (aliased)
                  const float* __restrict__ nW1,
                  const float* __restrict__ nb1)
{
    int n = blockIdx.x * 256 + threadIdx.x;
    if (n >= N_NODES) return;
    float acc[H_NF];
    #pragma unroll
    for (int j = 0; j < H_NF; ++j) acc[j] = nb1[j];
    const float* nfp = node_feats + n * NODE_NF;
    #pragma unroll 1
    for (int k = 0; k < NODE_NF; ++k) {
        float x = nfp[k];
        const float* w = nW1 + k * H_NF;
        #pragma unroll
        for (int j = 0; j < H_NF; ++j) acc[j] = fmaf(x, w[j], acc[j]);
    }
    #pragma unroll 1
    for (int k = 0; k < H_NF; ++k) {
        float x = agg_nh[k * N_NODES + n];
        const float* w = nW1 + (NODE_NF + k) * H_NF;
        #pragma unroll
        for (int j = 0; j < H_NF; ++j) acc[j] = fmaf(x, w[j], acc[j]);
    }
    #pragma unroll
    for (int j = 0; j < H_NF; ++j)
        agg_nh[j * N_NODES + n] = fmaxf(acc[j], 0.f);
}

// ---------------------------------------------------------------------------
// Node kernel 2: h = n_h @ nW2 + nb2 (no relu), out = h @ fW + fb.
// fc_emb fused (h never materialized). float4 output store.
// ---------------------------------------------------------------------------
__global__ __launch_bounds__(256)
void node_kernel2(const float* __restrict__ nh,  // [H][N]
                  const float* __restrict__ nW2,
                  const float* __restrict__ nb2,
                  const float* __restrict__ fW,
                  const float* __restrict__ fb,
                  float* __restrict__ out)
{
    int n = blockIdx.x * 256 + threadIdx.x;
    if (n >= N_NODES) return;
    float acc[H_NF];
    #pragma unroll
    for (int j = 0; j < H_NF; ++j) acc[j] = nb2[j];
    #pragma unroll 1
    for (int k = 0; k < H_NF; ++k) {
        float x = nh[k * N_NODES + n];
        const float* w = nW2 + k * H_NF;
        #pragma unroll
        for (int j = 0; j < H_NF; ++j) acc[j] = fmaf(x, w[j], acc[j]);
    }
    float o0 = fb[0], o1 = fb[1], o2 = fb[2], o3 = fb[3];
    #pragma unroll
    for (int j = 0; j < H_NF; ++j) {
        o0 = fmaf(acc[j], fW[j * 4 + 0], o0);
        o1 = fmaf(acc[j], fW[j * 4 + 1], o1);
        o2 = fmaf(acc[j], fW[j * 4 + 2], o2);
        o3 = fmaf(acc[j], fW[j * 4 + 3], o3);
    }
    float4 o = make_float4(o0, o1, o2, o3);
    ((float4*)out)[n] = o;
}

extern "C" void kernel_launch(void* const* d_in, const int* in_sizes, int n_in,
                              void* d_out, int out_size, void* d_ws, size_t ws_size,
                              hipStream_t stream)
{
    const float* node_feats = (const float*)d_in[0];
    const int*   edge_index = (const int*)d_in[1];
    const float* edge_attr  = (const float*)d_in[2];
    const float* eW1 = (const float*)d_in[3];
    const float* eb1 = (const float*)d_in[4];
    const float* eW2 = (const float*)d_in[5];
    const float* eb2 = (const float*)d_in[6];
    const float* nW1 = (const float*)d_in[7];
    const float* nb1 = (const float*)d_in[8];
    const float* nW2 = (const float*)d_in[9];
    const float* nb2 = (const float*)d_in[10];
    const float* fW  = (const float*)d_in[11];
    const float* fb  = (const float*)d_in[12];
    float* out = (float*)d_out;

    const size_t AGG_BYTES = (size_t)H_NF * N_NODES * sizeof(float);  // 51.2 MB
    float* agg = (float*)d_ws;
    float* W2T = (float*)((char*)d_ws + AGG_BYTES);                   // +64 KB

    hipMemsetAsync(agg, 0, AGG_BYTES, stream);
    transpose_w2<<<(H_NF * H_NF + 255) / 256, 256, 0, stream>>>(eW2, W2T);
    edge_kernel<<<(N_EDGES + 255) / 256, 256, 0, stream>>>(
        node_feats, edge_index, edge_attr, eW1, eb1, W2T, eb2, agg);
    node_kernel1<<<(N_NODES + 255) / 256, 256, 0, stream>>>(node_feats, agg, nW1, nb1);
    node_kernel2<<<(N_NODES + 255) / 256, 256, 0, stream>>>(agg, nW2, nb2, fW, fb, out);
}